// Round 7
// baseline (861.227 us; speedup 1.0000x reference)
//
#include <hip/hip_runtime.h>
#include <hip/hip_bf16.h>

#define T_STEPS 512
#define BATCH   4096
#define ACT     16
#define HDIM    64

typedef short s8v __attribute__((ext_vector_type(8)));   // 8 bf16 MFMA A/B frag
typedef float f4v __attribute__((ext_vector_type(4)));   // MFMA C/D frag

#define MFMA16(A, B, C) __builtin_amdgcn_mfma_f32_16x16x32_bf16((A), (B), (C), 0, 0, 0)

__device__ __forceinline__ unsigned pkbf(float a, float b) {
    unsigned r;
    asm("v_cvt_pk_bf16_f32 %0, %1, %2" : "=v"(r) : "v"(a), "v"(b));
    return r;   // low16 = bf16(a), high16 = bf16(b)
}
__device__ __forceinline__ float hi16f(unsigned p) { return __builtin_bit_cast(float, p & 0xFFFF0000u); }
__device__ __forceinline__ unsigned short f2bf(float f) {
    unsigned u = __builtin_bit_cast(unsigned, f);
    u += 0x7FFFu + ((u >> 16) & 1u);
    return (unsigned short)(u >> 16);
}
__device__ __forceinline__ float bf2f(unsigned short b) {
    return __builtin_bit_cast(float, ((unsigned)b) << 16);
}
// tanh(x) = 1 - 2/(e^{2x}+1): exact at +-inf limits
__device__ __forceinline__ float ftanh(float x) {
    float e = __expf(2.0f * x);
    return fmaf(-2.0f, __builtin_amdgcn_rcpf(e + 1.0f), 1.0f);
}
struct i4x { int a, b, c, d; };
// 4 f32 -> interleaved (hi,lo) bf16 pairs: element 2j = bf16(v[j]), 2j+1 = bf16(residual)
__device__ __forceinline__ s8v pack4(f4v v) {
    unsigned p0 = pkbf(v[0], v[0]); float r0 = v[0] - hi16f(p0);
    unsigned p1 = pkbf(v[1], v[1]); float r1 = v[1] - hi16f(p1);
    unsigned p2 = pkbf(v[2], v[2]); float r2 = v[2] - hi16f(p2);
    unsigned p3 = pkbf(v[3], v[3]); float r3 = v[3] - hi16f(p3);
    i4x w{(int)pkbf(v[0], r0), (int)pkbf(v[1], r1), (int)pkbf(v[2], r2), (int)pkbf(v[3], r3)};
    return __builtin_bit_cast(s8v, w);
}
// raw barrier: drain LDS only; global loads/stores stay in flight
#define BAR() do { \
    asm volatile("s_waitcnt lgkmcnt(0)" ::: "memory"); \
    __builtin_amdgcn_s_barrier(); \
    asm volatile("" ::: "memory"); \
} while (0)

// Swapped-operand MFMA cell: D = mfma(A=W^T frags, B=activation^T frags) makes
// D land as (col = batch row m, regs = 4 out-chs). With hi/lo-interleaved K
// (weights duplicated), the next layer's B-frag for lane (m,q) is exactly this
// lane's own D regs of tile f -> the whole chain stays in registers.
// 2 waves/block: wave0 = recurrence, wave1 = capture(z1). Only LDS: z1 handoff.
__global__ __launch_bounds__(128, 1) void fused_cell(
    const float* __restrict__ x,  const float* __restrict__ h0,
    const float* __restrict__ g,  const float* __restrict__ a,
    const float* __restrict__ Wc1, const float* __restrict__ bc1,
    const float* __restrict__ Wc2, const float* __restrict__ bc2,
    const float* __restrict__ Wp1, const float* __restrict__ bp1,
    const float* __restrict__ Wp2, const float* __restrict__ bp2,
    float* __restrict__ outs, float* __restrict__ hfin, float* __restrict__ capt)
{
    __shared__ float z1lds[2][16 * 64];   // [buf][m][ch], 16B chunks XOR-swizzled

    const int tid = threadIdx.x;
    const int l   = tid & 63;
    const bool capw = tid >= 64;
    const int m   = l & 15;        // batch row (B-col / D-col); also out-ch slot for A-frags
    const int q   = l >> 4;        // k-group / D row-group
    const int b0  = blockIdx.x << 4;
    const long ostep = (long)BATCH * HDIM;

    if (!capw) {
        // ================= RECURRENCE WAVE =================
        // weights (A-frags, swapped, dup-interleaved K)
        s8v W1[4][5];            // [tile][frag]; f=4 is the a-part (Wp1 rows 64..79)
        s8v W2h[4][4], W2l[4][4];
        f4v b1v[4], b2v[4];
        #pragma unroll
        for (int T = 0; T < 4; ++T) {
            #pragma unroll
            for (int f = 0; f < 4; ++f) {
                #pragma unroll
                for (int e = 0; e < 8; ++e) {
                    const int j = f * 16 + q * 4 + (e >> 1);
                    W1[T][f][e] = (short)f2bf(Wp1[j * 64 + 16 * T + m]);
                    float v2 = Wp2[j * 64 + 16 * T + m];
                    unsigned short h2 = f2bf(v2);
                    W2h[T][f][e] = (short)h2;
                    W2l[T][f][e] = (short)f2bf(v2 - bf2f(h2));
                }
            }
            #pragma unroll
            for (int e = 0; e < 8; ++e) {
                const int j = 64 + q * 4 + (e >> 1);
                W1[T][4][e] = (short)f2bf(Wp1[j * 64 + 16 * T + m]);
            }
            b1v[T] = *(const f4v*)&bp1[16 * T + 4 * q];
            b2v[T] = *(const f4v*)&bp2[16 * T + 4 * q];
        }
        // h0 -> B-frags (in-register state)
        s8v hfr[4];
        #pragma unroll
        for (int T = 0; T < 4; ++T)
            hfr[T] = pack4(*(const f4v*)&h0[(long)(b0 + m) * 64 + 16 * T + 4 * q]);
        // prime a[0], g[0]
        f4v aC = *(const f4v*)&a[(long)(b0 + m) * ACT + 4 * q];
        float gC = g[b0 + m];

        __syncthreads();   // capture has published z1[0] into buf0

        const float* zrd = &z1lds[0][0];
        float* outp = &outs[(long)(b0 + m) * 64 + 4 * q];
        f4v hoX[4];

        for (int t = 0; t < T_STEPS; ++t) {
            // early z1[t] reads (consumed after L2)
            f4v z1v[4];
            #pragma unroll
            for (int T = 0; T < 4; ++T) {
                const int ch = ((T << 2) | q) ^ (m & 7);
                z1v[T] = *(const f4v*)(zrd + m * 64 + ch * 4);
            }
            // prefetch a,g for t+1
            const int tn = (t + 1 < T_STEPS) ? t + 1 : T_STEPS - 1;
            f4v aN = *(const f4v*)&a[((long)tn * BATCH + b0 + m) * ACT + 4 * q];
            float gN = g[(long)tn * BATCH + b0 + m];

            s8v afr = pack4(aC);
            // ---- layer 1 (swapped): t1^T tiles ----
            s8v t1fr[4];
            #pragma unroll
            for (int T = 0; T < 4; ++T) {
                f4v a0 = b1v[T];
                f4v a1 = {0.f, 0.f, 0.f, 0.f};
                a0 = MFMA16(W1[T][0], hfr[0], a0);
                a1 = MFMA16(W1[T][1], hfr[1], a1);
                a0 = MFMA16(W1[T][2], hfr[2], a0);
                a1 = MFMA16(W1[T][3], hfr[3], a1);
                a0 = MFMA16(W1[T][4], afr,    a0);
                f4v tv;
                #pragma unroll
                for (int r = 0; r < 4; ++r) tv[r] = ftanh(a0[r] + a1[r]);
                t1fr[T] = pack4(tv);
            }
            // ---- layer 2 (swapped) + blend ----
            #pragma unroll
            for (int T = 0; T < 4; ++T) {
                f4v c0 = b2v[T];
                f4v c1 = {0.f, 0.f, 0.f, 0.f};
                c0 = MFMA16(W2h[T][0], t1fr[0], c0);
                c1 = MFMA16(W2h[T][1], t1fr[1], c1);
                c0 = MFMA16(W2h[T][2], t1fr[2], c0);
                c1 = MFMA16(W2h[T][3], t1fr[3], c1);
                c0 = MFMA16(W2l[T][0], t1fr[0], c0);
                c1 = MFMA16(W2l[T][1], t1fr[1], c1);
                c0 = MFMA16(W2l[T][2], t1fr[2], c0);
                c1 = MFMA16(W2l[T][3], t1fr[3], c1);
                f4v hv;
                #pragma unroll
                for (int r = 0; r < 4; ++r) {
                    float z2 = ftanh(c0[r] + c1[r]);
                    hv[r] = fmaf(gC, z2 - z1v[T][r], z1v[T][r]);
                }
                *(f4v*)(outp + 16 * T) = hv;
                hfr[T] = pack4(hv);
                hoX[T] = hv;
            }
            outp += ostep;
            aC = aN; gC = gN;
            zrd = (t & 1) ? &z1lds[0][0] : &z1lds[1][0];   // next read buf[(t+1)&1]
            BAR();
        }
        #pragma unroll
        for (int T = 0; T < 4; ++T)
            *(f4v*)&hfin[(long)(b0 + m) * 64 + 16 * T + 4 * q] = hoX[T];

    } else {
        // ================= CAPTURE WAVE =================
        s8v C1[4][4], C2h[4][4], C2l[4][4];
        f4v d1v[4], d2v[4];
        #pragma unroll
        for (int T = 0; T < 4; ++T) {
            #pragma unroll
            for (int f = 0; f < 4; ++f) {
                #pragma unroll
                for (int e = 0; e < 8; ++e) {
                    const int j = f * 16 + q * 4 + (e >> 1);
                    C1[T][f][e] = (short)f2bf(Wc1[j * 64 + 16 * T + m]);
                    float v2 = Wc2[j * 64 + 16 * T + m];
                    unsigned short h2 = f2bf(v2);
                    C2h[T][f][e] = (short)h2;
                    C2l[T][f][e] = (short)f2bf(v2 - bf2f(h2));
                }
            }
            d1v[T] = *(const f4v*)&bc1[16 * T + 4 * q];
            d2v[T] = *(const f4v*)&bc2[16 * T + 4 * q];
        }
        // ---- prologue: z1[0] from x[0] ----
        f4v XC[4];
        s8v xf[4];
        #pragma unroll
        for (int T = 0; T < 4; ++T)
            xf[T] = pack4(*(const f4v*)&x[(long)(b0 + m) * 64 + 16 * T + 4 * q]);
        s8v tcf[4];
        #pragma unroll
        for (int T = 0; T < 4; ++T) {
            f4v a0 = d1v[T];
            f4v a1 = {0.f, 0.f, 0.f, 0.f};
            a0 = MFMA16(C1[T][0], xf[0], a0);
            a1 = MFMA16(C1[T][1], xf[1], a1);
            a0 = MFMA16(C1[T][2], xf[2], a0);
            a1 = MFMA16(C1[T][3], xf[3], a1);
            f4v tv;
            #pragma unroll
            for (int r = 0; r < 4; ++r) tv[r] = ftanh(a0[r] + a1[r]);
            tcf[T] = pack4(tv);
        }
        #pragma unroll
        for (int T = 0; T < 4; ++T) {
            f4v c0 = d2v[T];
            f4v c1 = {0.f, 0.f, 0.f, 0.f};
            c0 = MFMA16(C2h[T][0], tcf[0], c0);
            c1 = MFMA16(C2h[T][1], tcf[1], c1);
            c0 = MFMA16(C2h[T][2], tcf[2], c0);
            c1 = MFMA16(C2h[T][3], tcf[3], c1);
            c0 = MFMA16(C2l[T][0], tcf[0], c0);
            c1 = MFMA16(C2l[T][1], tcf[1], c1);
            c0 = MFMA16(C2l[T][2], tcf[2], c0);
            c1 = MFMA16(C2l[T][3], tcf[3], c1);
            f4v zv;
            #pragma unroll
            for (int r = 0; r < 4; ++r) zv[r] = ftanh(c0[r] + c1[r]);
            const int ch = ((T << 2) | q) ^ (m & 7);
            *(f4v*)(&z1lds[0][0] + m * 64 + ch * 4) = zv;
            *(f4v*)&capt[(long)(b0 + m) * 64 + 16 * T + 4 * q] = zv;
        }
        // prime x[1]
        #pragma unroll
        for (int T = 0; T < 4; ++T)
            XC[T] = *(const f4v*)&x[((long)BATCH + b0 + m) * 64 + 16 * T + 4 * q];

        __syncthreads();   // z1[0] published

        float* zwr = &z1lds[1][0];                      // step t writes buf[(t+1)&1]
        float* cp  = &capt[((long)BATCH + b0 + m) * 64 + 4 * q];   // capt[1] base

        for (int t = 0; t < T_STEPS; ++t) {
            // prefetch x[t+2]
            const int tn2 = (t + 2 < T_STEPS) ? t + 2 : T_STEPS - 1;
            f4v XN[4];
            #pragma unroll
            for (int T = 0; T < 4; ++T)
                XN[T] = *(const f4v*)&x[((long)tn2 * BATCH + b0 + m) * 64 + 16 * T + 4 * q];

            #pragma unroll
            for (int T = 0; T < 4; ++T) xf[T] = pack4(XC[T]);
            // L1
            #pragma unroll
            for (int T = 0; T < 4; ++T) {
                f4v a0 = d1v[T];
                f4v a1 = {0.f, 0.f, 0.f, 0.f};
                a0 = MFMA16(C1[T][0], xf[0], a0);
                a1 = MFMA16(C1[T][1], xf[1], a1);
                a0 = MFMA16(C1[T][2], xf[2], a0);
                a1 = MFMA16(C1[T][3], xf[3], a1);
                f4v tv;
                #pragma unroll
                for (int r = 0; r < 4; ++r) tv[r] = ftanh(a0[r] + a1[r]);
                tcf[T] = pack4(tv);
            }
            // L2 -> z1[t+1]
            #pragma unroll
            for (int T = 0; T < 4; ++T) {
                f4v c0 = d2v[T];
                f4v c1 = {0.f, 0.f, 0.f, 0.f};
                c0 = MFMA16(C2h[T][0], tcf[0], c0);
                c1 = MFMA16(C2h[T][1], tcf[1], c1);
                c0 = MFMA16(C2h[T][2], tcf[2], c0);
                c1 = MFMA16(C2h[T][3], tcf[3], c1);
                c0 = MFMA16(C2l[T][0], tcf[0], c0);
                c1 = MFMA16(C2l[T][1], tcf[1], c1);
                c0 = MFMA16(C2l[T][2], tcf[2], c0);
                c1 = MFMA16(C2l[T][3], tcf[3], c1);
                f4v zv;
                #pragma unroll
                for (int r = 0; r < 4; ++r) zv[r] = ftanh(c0[r] + c1[r]);
                const int ch = ((T << 2) | q) ^ (m & 7);
                *(f4v*)(zwr + m * 64 + ch * 4) = zv;
                if (t < T_STEPS - 1) *(f4v*)(cp + 16 * T) = zv;
            }
            cp += ostep;
            #pragma unroll
            for (int T = 0; T < 4; ++T) XC[T] = XN[T];
            zwr = (t & 1) ? &z1lds[1][0] : &z1lds[0][0];   // next write buf[(t+2)&1]
            BAR();
        }
    }
}

extern "C" void kernel_launch(void* const* d_in, const int* in_sizes, int n_in,
                              void* d_out, int out_size, void* d_ws, size_t ws_size,
                              hipStream_t stream) {
    const float* x   = (const float*)d_in[0];
    const float* h0  = (const float*)d_in[1];
    const float* g   = (const float*)d_in[2];
    const float* a   = (const float*)d_in[3];
    const float* Wc1 = (const float*)d_in[4];
    const float* bc1 = (const float*)d_in[5];
    const float* Wc2 = (const float*)d_in[6];
    const float* bc2 = (const float*)d_in[7];
    const float* Wp1 = (const float*)d_in[8];
    const float* bp1 = (const float*)d_in[9];
    const float* Wp2 = (const float*)d_in[10];
    const float* bp2 = (const float*)d_in[11];

    float* outs = (float*)d_out;
    float* hfin = outs + (long)T_STEPS * BATCH * HDIM;
    float* capt = hfin + (long)BATCH * HDIM;

    fused_cell<<<BATCH / 16, 128, 0, stream>>>(
        x, h0, g, a, Wc1, bc1, Wc2, bc2, Wp1, bp1, Wp2, bp2, outs, hfin, capt);
}

// Round 8
// 604.962 us; speedup vs baseline: 1.4236x; 1.4236x over previous
//
#include <hip/hip_runtime.h>
#include <hip/hip_bf16.h>

#define T_STEPS 512
#define BATCH   4096
#define ACT     16
#define HDIM    64

typedef short s8v __attribute__((ext_vector_type(8)));   // 8 bf16 MFMA A/B frag
typedef float f4v __attribute__((ext_vector_type(4)));   // MFMA C/D frag

#define MFMA16(A, B, C) __builtin_amdgcn_mfma_f32_16x16x32_bf16((A), (B), (C), 0, 0, 0)

__device__ __forceinline__ unsigned pkbf(float a, float b) {
    unsigned r;
    asm("v_cvt_pk_bf16_f32 %0, %1, %2" : "=v"(r) : "v"(a), "v"(b));
    return r;   // low16 = bf16(a), high16 = bf16(b)
}
__device__ __forceinline__ float hi16f(unsigned p) { return __builtin_bit_cast(float, p & 0xFFFF0000u); }
__device__ __forceinline__ unsigned short f2bf(float f) {
    unsigned u = __builtin_bit_cast(unsigned, f);
    u += 0x7FFFu + ((u >> 16) & 1u);
    return (unsigned short)(u >> 16);
}
__device__ __forceinline__ float bf2f(unsigned short b) {
    return __builtin_bit_cast(float, ((unsigned)b) << 16);
}
// tanh(x) = 1 - 2/(e^{2x}+1): exact at +-inf limits
__device__ __forceinline__ float ftanh(float x) {
    float e = __expf(2.0f * x);
    return fmaf(-2.0f, __builtin_amdgcn_rcpf(e + 1.0f), 1.0f);
}
struct i4x { int a, b, c, d; };
// 4 f32 -> interleaved (hi,lo) bf16 pairs: element 2j = bf16(v[j]), 2j+1 = bf16(residual)
__device__ __forceinline__ s8v pack4(f4v v) {
    unsigned p0 = pkbf(v[0], v[0]); float r0 = v[0] - hi16f(p0);
    unsigned p1 = pkbf(v[1], v[1]); float r1 = v[1] - hi16f(p1);
    unsigned p2 = pkbf(v[2], v[2]); float r2 = v[2] - hi16f(p2);
    unsigned p3 = pkbf(v[3], v[3]); float r3 = v[3] - hi16f(p3);
    i4x w{(int)pkbf(v[0], r0), (int)pkbf(v[1], r1), (int)pkbf(v[2], r2), (int)pkbf(v[3], r3)};
    return __builtin_bit_cast(s8v, w);
}
// raw barrier: drain LDS only; global loads/stores stay in flight
#define BAR() do { \
    asm volatile("s_waitcnt lgkmcnt(0)" ::: "memory"); \
    __builtin_amdgcn_s_barrier(); \
    asm volatile("" ::: "memory"); \
} while (0)

// ================= K1: capture (z1 for all T*B rows) =================
// grid-strided 16-row tiles, all state in registers, x software-pipelined.
__global__ __launch_bounds__(256, 1) void capture_k(
    const float* __restrict__ x,
    const float* __restrict__ Wc1, const float* __restrict__ bc1,
    const float* __restrict__ Wc2, const float* __restrict__ bc2,
    float* __restrict__ capt)
{
    const int tid = threadIdx.x;
    const int l   = tid & 63;
    const int m   = l & 15;
    const int q   = l >> 4;
    const int gw  = blockIdx.x * 4 + (tid >> 6);   // 0..1023
    const int NW  = 1024;
    const long NT = (long)T_STEPS * BATCH / 16;    // 131072 tiles

    s8v C1[4][4], C2h[4][4], C2l[4][4];
    f4v d1v[4], d2v[4];
    #pragma unroll
    for (int T = 0; T < 4; ++T) {
        #pragma unroll
        for (int f = 0; f < 4; ++f) {
            #pragma unroll
            for (int e = 0; e < 8; ++e) {
                const int j = f * 16 + q * 4 + (e >> 1);
                C1[T][f][e] = (short)f2bf(Wc1[j * 64 + 16 * T + m]);
                float v2 = Wc2[j * 64 + 16 * T + m];
                unsigned short h2 = f2bf(v2);
                C2h[T][f][e] = (short)h2;
                C2l[T][f][e] = (short)f2bf(v2 - bf2f(h2));
            }
        }
        d1v[T] = *(const f4v*)&bc1[16 * T + 4 * q];
        d2v[T] = *(const f4v*)&bc2[16 * T + 4 * q];
    }

    long tile = gw;
    if (tile >= NT) return;
    f4v XC[4];
    #pragma unroll
    for (int f = 0; f < 4; ++f)
        XC[f] = *(const f4v*)&x[(tile * 16 + m) * 64 + 16 * f + 4 * q];

    for (; tile < NT; tile += NW) {
        const long nxt = (tile + NW < NT) ? tile + NW : tile;
        f4v XN[4];
        #pragma unroll
        for (int f = 0; f < 4; ++f)
            XN[f] = *(const f4v*)&x[(nxt * 16 + m) * 64 + 16 * f + 4 * q];

        s8v xf[4];
        #pragma unroll
        for (int f = 0; f < 4; ++f) xf[f] = pack4(XC[f]);

        s8v tcf[4];
        #pragma unroll
        for (int T = 0; T < 4; ++T) {
            f4v u0 = d1v[T];
            f4v u1 = {0.f, 0.f, 0.f, 0.f};
            u0 = MFMA16(C1[T][0], xf[0], u0);
            u1 = MFMA16(C1[T][1], xf[1], u1);
            u0 = MFMA16(C1[T][2], xf[2], u0);
            u1 = MFMA16(C1[T][3], xf[3], u1);
            f4v tv;
            #pragma unroll
            for (int r = 0; r < 4; ++r) tv[r] = ftanh(u0[r] + u1[r]);
            tcf[T] = pack4(tv);
        }
        #pragma unroll
        for (int T = 0; T < 4; ++T) {
            f4v c0 = d2v[T];
            f4v c1 = {0.f, 0.f, 0.f, 0.f}, c2 = c1, c3 = c1;
            c0 = MFMA16(C2h[T][0], tcf[0], c0);
            c1 = MFMA16(C2h[T][1], tcf[1], c1);
            c2 = MFMA16(C2h[T][2], tcf[2], c2);
            c3 = MFMA16(C2h[T][3], tcf[3], c3);
            c0 = MFMA16(C2l[T][0], tcf[0], c0);
            c1 = MFMA16(C2l[T][1], tcf[1], c1);
            c2 = MFMA16(C2l[T][2], tcf[2], c2);
            c3 = MFMA16(C2l[T][3], tcf[3], c3);
            f4v zv;
            #pragma unroll
            for (int r = 0; r < 4; ++r) zv[r] = ftanh((c0[r] + c1[r]) + (c2[r] + c3[r]));
            *(f4v*)&capt[(tile * 16 + m) * 64 + 16 * T + 4 * q] = zv;
        }
        #pragma unroll
        for (int f = 0; f < 4; ++f) XC[f] = XN[f];
    }
}

// ================= K2: recurrence, slice split across 4 waves =================
// Wave T owns output-channel tile T. Exchange of h/t1 fragments is lane-preserving:
// wave T's packed s8v at lane l IS frag f=T for lane l of every wave.
__global__ __launch_bounds__(256, 1) void recur_k(
    const float* __restrict__ h0, const float* __restrict__ g,
    const float* __restrict__ a,  const float* __restrict__ Wp1,
    const float* __restrict__ bp1, const float* __restrict__ Wp2,
    const float* __restrict__ bp2, const float* __restrict__ z1,
    float* __restrict__ outs, float* __restrict__ hfin)
{
    __shared__ s8v hx[4][64];
    __shared__ s8v t1x[4][64];

    const int tid = threadIdx.x;
    const int T   = tid >> 6;      // owned tile
    const int l   = tid & 63;
    const int m   = l & 15;
    const int q   = l >> 4;
    const int b0  = blockIdx.x << 4;

    // ---- own-tile weights ----
    s8v W1[5], W2h[4], W2l[4];
    #pragma unroll
    for (int f = 0; f < 4; ++f) {
        #pragma unroll
        for (int e = 0; e < 8; ++e) {
            const int j = f * 16 + q * 4 + (e >> 1);
            W1[f][e] = (short)f2bf(Wp1[j * 64 + 16 * T + m]);
            float v2 = Wp2[j * 64 + 16 * T + m];
            unsigned short h2 = f2bf(v2);
            W2h[f][e] = (short)h2;
            W2l[f][e] = (short)f2bf(v2 - bf2f(h2));
        }
    }
    #pragma unroll
    for (int e = 0; e < 8; ++e) {
        const int j = 64 + q * 4 + (e >> 1);
        W1[4][e] = (short)f2bf(Wp1[j * 64 + 16 * T + m]);
    }
    const f4v b1v = *(const f4v*)&bp1[16 * T + 4 * q];
    const f4v b2v = *(const f4v*)&bp2[16 * T + 4 * q];

    // per-lane stream offsets (elements)
    const long zoff = (long)(b0 + m) * 64 + 16 * T + 4 * q;  // for z1/outs/hfin-style [b][ch]
    const long aoff = (long)(b0 + m) * ACT + 4 * q;
    const long goff = (long)(b0 + m);

    // ---- prologue: own h0 tile -> LDS; depth-4 prefetch ring ----
    {
        f4v h0v = *(const f4v*)&h0[zoff];
        hx[T][l] = pack4(h0v);
    }
    f4v zP0 = *(const f4v*)&z1[0 * (long)BATCH * 64 + zoff];
    f4v zP1 = *(const f4v*)&z1[1 * (long)BATCH * 64 + zoff];
    f4v zP2 = *(const f4v*)&z1[2 * (long)BATCH * 64 + zoff];
    f4v zP3 = *(const f4v*)&z1[3 * (long)BATCH * 64 + zoff];
    f4v aP0 = *(const f4v*)&a[0 * (long)BATCH * ACT + aoff];
    f4v aP1 = *(const f4v*)&a[1 * (long)BATCH * ACT + aoff];
    f4v aP2 = *(const f4v*)&a[2 * (long)BATCH * ACT + aoff];
    f4v aP3 = *(const f4v*)&a[3 * (long)BATCH * ACT + aoff];
    float gP0 = g[0 * (long)BATCH + goff];
    float gP1 = g[1 * (long)BATCH + goff];
    float gP2 = g[2 * (long)BATCH + goff];
    float gP3 = g[3 * (long)BATCH + goff];

    float* outp = &outs[zoff];
    f4v hl = {0.f, 0.f, 0.f, 0.f};
    __syncthreads();

#define RSTEP(tt, ZP, AP, GP) {                                               \
    /* ---- phase 1: L1 on all-h frags ---- */                                \
    s8v hf0 = hx[0][l];                                                       \
    s8v hf1 = hx[1][l];                                                       \
    s8v hf2 = hx[2][l];                                                       \
    s8v hf3 = hx[3][l];                                                       \
    s8v afr = pack4(AP);                                                      \
    f4v p0 = b1v;                                                             \
    f4v p1 = {0.f, 0.f, 0.f, 0.f}, p2 = p1;                                   \
    p0 = MFMA16(W1[0], hf0, p0);                                              \
    p1 = MFMA16(W1[1], hf1, p1);                                              \
    p2 = MFMA16(W1[2], hf2, p2);                                              \
    p0 = MFMA16(W1[3], hf3, p0);                                              \
    p1 = MFMA16(W1[4], afr, p1);                                              \
    f4v tv;                                                                   \
    _Pragma("unroll")                                                         \
    for (int r = 0; r < 4; ++r) tv[r] = ftanh((p0[r] + p1[r]) + p2[r]);       \
    t1x[T][l] = pack4(tv);                                                    \
    BAR();                                                                    \
    /* ---- phase 2: L2 + blend ---- */                                       \
    s8v tf0 = t1x[0][l];                                                      \
    s8v tf1 = t1x[1][l];                                                      \
    s8v tf2 = t1x[2][l];                                                      \
    s8v tf3 = t1x[3][l];                                                      \
    f4v c0 = b2v;                                                             \
    f4v c1 = {0.f, 0.f, 0.f, 0.f}, c2 = c1, c3 = c1;                          \
    c0 = MFMA16(W2h[0], tf0, c0);                                             \
    c1 = MFMA16(W2h[1], tf1, c1);                                             \
    c2 = MFMA16(W2h[2], tf2, c2);                                             \
    c3 = MFMA16(W2h[3], tf3, c3);                                             \
    c0 = MFMA16(W2l[0], tf0, c0);                                             \
    c1 = MFMA16(W2l[1], tf1, c1);                                             \
    c2 = MFMA16(W2l[2], tf2, c2);                                             \
    c3 = MFMA16(W2l[3], tf3, c3);                                             \
    f4v hv;                                                                   \
    _Pragma("unroll")                                                         \
    for (int r = 0; r < 4; ++r) {                                             \
        float z2 = ftanh((c0[r] + c1[r]) + (c2[r] + c3[r]));                  \
        hv[r] = fmaf(GP, z2 - ZP[r], ZP[r]);                                  \
    }                                                                         \
    *(f4v*)outp = hv;                                                         \
    outp += (long)BATCH * HDIM;                                               \
    hl = hv;                                                                  \
    hx[T][l] = pack4(hv);                                                     \
    /* ---- refill ring slot for tt+4 ---- */                                 \
    {                                                                         \
        const long tn = ((tt) + 4 < T_STEPS) ? (tt) + 4 : T_STEPS - 1;        \
        ZP = *(const f4v*)&z1[tn * (long)BATCH * 64 + zoff];                  \
        AP = *(const f4v*)&a[tn * (long)BATCH * ACT + aoff];                  \
        GP = g[tn * (long)BATCH + goff];                                      \
    }                                                                         \
    BAR();                                                                    \
}

    for (int t = 0; t < T_STEPS; t += 4) {
        RSTEP(t + 0, zP0, aP0, gP0);
        RSTEP(t + 1, zP1, aP1, gP1);
        RSTEP(t + 2, zP2, aP2, gP2);
        RSTEP(t + 3, zP3, aP3, gP3);
    }
#undef RSTEP

    *(f4v*)&hfin[zoff] = hl;
}

extern "C" void kernel_launch(void* const* d_in, const int* in_sizes, int n_in,
                              void* d_out, int out_size, void* d_ws, size_t ws_size,
                              hipStream_t stream) {
    const float* x   = (const float*)d_in[0];
    const float* h0  = (const float*)d_in[1];
    const float* g   = (const float*)d_in[2];
    const float* a   = (const float*)d_in[3];
    const float* Wc1 = (const float*)d_in[4];
    const float* bc1 = (const float*)d_in[5];
    const float* Wc2 = (const float*)d_in[6];
    const float* bc2 = (const float*)d_in[7];
    const float* Wp1 = (const float*)d_in[8];
    const float* bp1 = (const float*)d_in[9];
    const float* Wp2 = (const float*)d_in[10];
    const float* bp2 = (const float*)d_in[11];

    float* outs = (float*)d_out;
    float* hfin = outs + (long)T_STEPS * BATCH * HDIM;
    float* capt = hfin + (long)BATCH * HDIM;

    capture_k<<<256, 256, 0, stream>>>(x, Wc1, bc1, Wc2, bc2, capt);
    recur_k<<<BATCH / 16, 256, 0, stream>>>(h0, g, a, Wp1, bp1, Wp2, bp2, capt, outs, hfin);
}